// Round 13
// baseline (176.906 us; speedup 1.0000x reference)
//
#include <hip/hip_runtime.h>
#include <stdint.h>

#define AS1 __attribute__((address_space(1)))
#define AS3 __attribute__((address_space(3)))

typedef __bf16 bf16_t;
typedef bf16_t bf16x8 __attribute__((ext_vector_type(8)));
typedef float  f32x4  __attribute__((ext_vector_type(4)));
typedef float  f32x16 __attribute__((ext_vector_type(16)));
typedef unsigned short u16;

constexpr int D     = 1280;
constexpr int H     = 20;
constexpr int HD    = 64;
constexpr int NQ    = 1600;
constexpr int NKV   = 6000;
constexpr int ENC   = 1500;
constexpr int QPAD  = 1632;   // NQ padded so q-row reads past the end stay in-buffer
constexpr int KVP   = 1504;   // per-request kv rows padded to 32-multiple
constexpr int KVTOT = 4 * KVP;
constexpr int KB_PER_REQ = KVP / 32;      // 47
constexpr int KB_TOT     = 4 * KB_PER_REQ; // 188

__device__ __forceinline__ u16 f2bf(float f) {
  union { float f; uint32_t u; } x; x.f = f;
  uint32_t r = (x.u + 0x7fffu + ((x.u >> 16) & 1u)) >> 16;  // RNE
  return (u16)r;
}

__device__ __forceinline__ void gload16(const void* g, void* l) {
  __builtin_amdgcn_global_load_lds((AS1 void*)g, (AS3 void*)l, 16, 0, 0);
}

// ---------------- fused prep: fp32->bf16 converts + 3 weight transposes ----------------
__device__ __forceinline__ void cvt_body(const float* __restrict__ in, u16* __restrict__ out,
                                         int i, int n4) {
  if (i >= n4) return;
  float4 v = ((const float4*)in)[i];
  ushort4 o;
  o.x = f2bf(v.x); o.y = f2bf(v.y); o.z = f2bf(v.z); o.w = f2bf(v.w);
  ((ushort4*)out)[i] = o;
}

__device__ __forceinline__ void tpose_body(const float* __restrict__ in, u16* __restrict__ out,
                                           int R, int C, int bx, int by, u16 (*tile)[33]) {
  int bc = bx * 32, br = by * 32;
  int tx = threadIdx.x & 31, ty = threadIdx.x >> 5;  // 32 x 8
#pragma unroll
  for (int i = 0; i < 32; i += 8)
    tile[ty + i][tx] = f2bf(in[(size_t)(br + ty + i) * C + bc + tx]);
  __syncthreads();
#pragma unroll
  for (int i = 0; i < 32; i += 8)
    out[(size_t)(bc + ty + i) * R + br + tx] = tile[tx][ty + i];
}

__global__ __launch_bounds__(256)
void prep_kernel(const float* __restrict__ hs, const float* __restrict__ chs,
                 const float* __restrict__ Wq, const float* __restrict__ Wkv,
                 const float* __restrict__ Wo,
                 u16* __restrict__ hsb, u16* __restrict__ chsb,
                 u16* __restrict__ Wqt, u16* __restrict__ Wkvt, u16* __restrict__ Wot) {
  __shared__ u16 tile[32][33];
  int b = blockIdx.x;
  if (b < 2000) {
    cvt_body(hs, hsb, b * 256 + threadIdx.x, 512000);
  } else if (b < 9500) {
    cvt_body(chs, chsb, (b - 2000) * 256 + threadIdx.x, 1920000);
  } else if (b < 11100) {
    int t = b - 9500;  tpose_body(Wq,  Wqt,  1280, 1280, t % 40, t / 40, tile);
  } else if (b < 14300) {
    int t = b - 11100; tpose_body(Wkv, Wkvt, 1280, 2560, t % 80, t / 80, tile);
  } else {
    int t = b - 14300; tpose_body(Wo,  Wot,  1280, 1280, t % 40, t / 40, tile);
  }
}

// ---------------- bf16 GEMM tile: C[M,N] = A[M,1280] @ Bt[N,1280]^T + bias ----------------
// R6-proven structure: 128x128 tile, 16x16x32 MFMA, 4 waves 2x2, single-buffer
// stage -> syncthreads -> compute -> syncthreads. (R7 dist-2 pipeline, R8 2-phase
// counted-vmcnt, R9 32x32 frags: all NULL or negative — do not re-graft. LDS-port
// arithmetic: 96 KB port traffic/tile/block vs 256 cy MFMA -> ~25% MfmaUtil ceiling;
// we run at 21%. Converged at this geometry.)
// MODE 0: Q-proj  -> qh[h][row][hd] = (c+b)*0.125          (bf16)
// MODE 1: KV-proj -> Kb[h][kb][ks:4][kv:32][e:16]  (K blocks, n0<1280)
//                    Vb[h][kb][d:64][kv:32]        (V blocks, n0>=1280: C^T via
//                    swapped MFMA operands so stores stay coalesced)
// MODE 2: O-proj  -> outF[row*1280+col] = c+b               (fp32)
template <int MODE>
__device__ __forceinline__ void gemm_tile(
    int m0, int n0, const u16* __restrict__ A, const u16* __restrict__ Bt,
    const float* __restrict__ bias, int M,
    u16* __restrict__ outA, u16* __restrict__ outB, float* __restrict__ outF,
    u16* As, u16* Bs) {
  const int tid = threadIdx.x;
  const int lane = tid & 63, l15 = lane & 15, lg = lane >> 4;
  const int w = tid >> 6, wr = w >> 1, wc = w & 1;

  const bool vside = (MODE == 1) && (n0 >= D);

  f32x4 acc[4][4] = {};

  for (int k0 = 0; k0 < D; k0 += 64) {
#pragma unroll
    for (int p = 0; p < 4; ++p) {
      int off = p * 4096 + tid * 16;
      int lg_off = off ^ (((off >> 7) & 7) << 4);
      int row = lg_off >> 7, kb = lg_off & 127;
      int gr = m0 + row; gr = gr < M ? gr : M - 1;  // clamp M-tail
      gload16((const char*)A + ((size_t)gr * D + k0) * 2 + kb, (char*)As + off);
    }
#pragma unroll
    for (int p = 0; p < 4; ++p) {
      int off = p * 4096 + tid * 16;
      int lg_off = off ^ (((off >> 7) & 7) << 4);
      int row = lg_off >> 7, kb = lg_off & 127;
      int gr = n0 + row;  // N is always a multiple of 128
      gload16((const char*)Bt + ((size_t)gr * D + k0) * 2 + kb, (char*)Bs + off);
    }
    __syncthreads();
#pragma unroll
    for (int kk = 0; kk < 2; ++kk) {
      const int kbyte = kk * 64 + lg * 16;
      bf16x8 af[4], bfr[4];
#pragma unroll
      for (int m = 0; m < 4; ++m) {
        int row = wr * 64 + m * 16 + l15;
        int addr = ((row << 7) + kbyte) ^ ((row & 7) << 4);
        af[m] = *(const bf16x8*)((const char*)As + addr);
      }
#pragma unroll
      for (int n = 0; n < 4; ++n) {
        int row = wc * 64 + n * 16 + l15;
        int addr = ((row << 7) + kbyte) ^ ((row & 7) << 4);
        bfr[n] = *(const bf16x8*)((const char*)Bs + addr);
      }
      if (!vside) {
#pragma unroll
        for (int m = 0; m < 4; ++m)
#pragma unroll
          for (int n = 0; n < 4; ++n)
            acc[m][n] = __builtin_amdgcn_mfma_f32_16x16x32_bf16(af[m], bfr[n], acc[m][n], 0, 0, 0);
      } else {
        // C^T: D[n][m] — lane dim (col) becomes the M/kv index
#pragma unroll
        for (int m = 0; m < 4; ++m)
#pragma unroll
          for (int n = 0; n < 4; ++n)
            acc[m][n] = __builtin_amdgcn_mfma_f32_16x16x32_bf16(bfr[n], af[m], acc[m][n], 0, 0, 0);
      }
    }
    __syncthreads();
  }

  if (!vside) {
    // C/D layout: col = n-idx = lane&15, row = m-idx = (lane>>4)*4 + reg
#pragma unroll
    for (int m = 0; m < 4; ++m)
#pragma unroll
      for (int n = 0; n < 4; ++n) {
        int col = n0 + wc * 64 + n * 16 + l15;
        float bv = bias[col];
#pragma unroll
        for (int r = 0; r < 4; ++r) {
          int row = m0 + wr * 64 + m * 16 + lg * 4 + r;
          if (row >= M) continue;
          float v = acc[m][n][r] + bv;
          if (MODE == 0) {
            v *= 0.125f;  // HD^-0.5
            int h = col >> 6, hd = col & 63;
            outA[((size_t)(h * QPAD + row)) * HD + hd] = f2bf(v);
          } else if (MODE == 1) {
            int req = row / ENC, loc = row - req * ENC;
            int rr = req * KVP + loc;
            int h = col >> 6, hd = col & 63;
            int kb2 = rr >> 5, kv = rr & 31;
            outA[((size_t)((h * KB_TOT + kb2) * 4 + (hd >> 4))) * 512 + kv * 16 + (hd & 15)] = f2bf(v);
          } else {
            outF[(size_t)row * D + col] = v;
          }
        }
      }
  } else {
    // C^T: lane&15 = kv-row offset; (lane>>4)*4+reg = output-col offset
    float bvv[4][4];
#pragma unroll
    for (int n = 0; n < 4; ++n)
#pragma unroll
      for (int r = 0; r < 4; ++r)
        bvv[n][r] = bias[n0 + wc * 64 + n * 16 + lg * 4 + r];
#pragma unroll
    for (int m = 0; m < 4; ++m) {
      int gm = m0 + wr * 64 + m * 16 + l15;  // kv row (per-lane)
      int req = gm / ENC, loc = gm - req * ENC;
      int rr = req * KVP + loc;
      int kb2 = rr >> 5, kv = rr & 31;
      bool ok = gm < M;
#pragma unroll
      for (int n = 0; n < 4; ++n)
#pragma unroll
        for (int r = 0; r < 4; ++r) {
          if (!ok) continue;
          int c2 = n0 + wc * 64 + n * 16 + lg * 4 + r - D;
          int h = c2 >> 6, hd = c2 & 63;
          outB[((size_t)((h * KB_TOT + kb2) * 64 + hd)) * 32 + kv] = f2bf(acc[m][n][r] + bvv[n][r]);
        }
    }
  }
}

// ---------------- fused Q-proj + KV-proj, per-range bijective XCD swizzle ----------------
__global__ __launch_bounds__(256)
void qkv_gemm_kernel(const u16* __restrict__ hsb, const u16* __restrict__ chsb,
                     const u16* __restrict__ Wqt, const u16* __restrict__ Wkvt,
                     const float* __restrict__ bq, const float* __restrict__ bkv,
                     u16* __restrict__ qhb, u16* __restrict__ khb, u16* __restrict__ vtb) {
  __shared__ __align__(16) u16 As[128 * 64];
  __shared__ __align__(16) u16 Bs[128 * 64];
  const int bid = blockIdx.x;
  if (bid < 940) {
    const int q8 = 940 >> 3, r8 = 940 & 7;  // 117, 4
    const int xcd = bid & 7, pos = bid >> 3;
    const int wg = (xcd < r8 ? xcd * (q8 + 1) : r8 * (q8 + 1) + (xcd - r8) * q8) + pos;
    gemm_tile<1>((wg / 20) * 128, (wg % 20) * 128, chsb, Wkvt, bkv, NKV,
                 khb, vtb, nullptr, As, Bs);
  } else {
    const int b2 = bid - 940;
    const int q8 = 130 >> 3, r8 = 130 & 7;  // 16, 2
    const int xcd = b2 & 7, pos = b2 >> 3;
    const int wg = (xcd < r8 ? xcd * (q8 + 1) : r8 * (q8 + 1) + (xcd - r8) * q8) + pos;
    gemm_tile<0>((wg / 10) * 128, (wg % 10) * 128, hsb, Wqt, bq, NQ,
                 qhb, nullptr, nullptr, As, Bs);
  }
}

__global__ __launch_bounds__(256)
void o_gemm_kernel(const u16* __restrict__ attnb, const u16* __restrict__ Wot,
                   const float* __restrict__ bo, float* __restrict__ out) {
  __shared__ __align__(16) u16 As[128 * 64];
  __shared__ __align__(16) u16 Bs[128 * 64];
  const int nwg = 130, q8 = nwg >> 3, r8 = nwg & 7;
  const int xcd = blockIdx.x & 7, pos = blockIdx.x >> 3;
  const int wg = (xcd < r8 ? xcd * (q8 + 1) : r8 * (q8 + 1) + (xcd - r8) * q8) + pos;
  gemm_tile<2>((wg / 10) * 128, (wg % 10) * 128, attnb, Wot, bo, NQ,
               nullptr, nullptr, out, As, Bs);
}

// ---------------- flash attention, swapped-QK^T 32x32, fixed-shift softmax, QBLK=64 ----
// 1D grid (640 = 8 xcd x 10 pairs x 8 q-tiles); each wave owns 64 q (2 column
// groups, processed sequentially per step) x its kv quarter. K/V loads amortize
// over 2x the MFMA/softmax work. Fixed shift M=16 (R11-verified). Q-row reads
// clamped to NQ-1 (garbage stays lane-local in the swapped layout; stores masked).
__global__ __launch_bounds__(256)
void attn_kernel(const u16* __restrict__ kbuf, const u16* __restrict__ vbuf,
                 const u16* __restrict__ qh, const int* __restrict__ seq,
                 u16* __restrict__ attnb) {
  __shared__ __align__(16) float smem[4][2176];
  const int lane = threadIdx.x & 63;
  const int l31 = lane & 31, h5 = lane >> 5;
  const int w = threadIdx.x >> 6;

  const int xcd = blockIdx.x & 7, pos = blockIdx.x >> 3;  // pos in [0,80)
  const int g = xcd * 80 + pos;
  const int p = g >> 3, t = g & 7;    // p in [0,80): (head,req) pair; t: q64-tile
  const int head = p >> 2, req = p & 3;

  int s0 = seq[0], s1 = seq[1], s2 = seq[2];
  int qstart = (req > 0 ? s0 : 0) + (req > 1 ? s1 : 0) + (req > 2 ? s2 : 0);
  int slen = seq[req];
  int q0 = t * 64;
  if (q0 >= slen) return;  // block-uniform: safe w.r.t. __syncthreads

  // Q B-frags for both 32-column groups; row index clamped to stay in-buffer
  bf16x8 qb[2][4];
#pragma unroll
  for (int qc = 0; qc < 2; ++qc) {
    int ri = qstart + q0 + qc * 32 + l31;
    ri = ri < NQ ? ri : NQ - 1;  // clamp: garbage q stays lane-local, store-masked
    const u16* qrow = qh + ((size_t)(head * QPAD + ri)) * HD + h5 * 8;
#pragma unroll
    for (int ks = 0; ks < 4; ++ks) qb[qc][ks] = *(const bf16x8*)(qrow + ks * 16);
  }

  const u16* kpan = kbuf + (size_t)(head * KB_TOT + req * KB_PER_REQ) * 2048 + l31 * 16 + h5 * 8;
  const u16* vpan = vbuf + (size_t)(head * KB_TOT + req * KB_PER_REQ) * 2048 + l31 * 32 + h5 * 8;
  const float C = 1.44269504088896340736f;
  const float KC = 16.0f * C;  // fixed softmax shift (scores bounded << 16)

  f32x16 o[2][2] = {};
  float ls[2] = {0.f, 0.f};

  const int kvs = w * 384;
  const int kve = (w == 3) ? ENC : kvs + 384;  // quarters: 384,384,384,348

  bf16x8 ka[4], va[2][2], kan[4], van[2][2];
  {
    const u16* kp = kpan + (size_t)(kvs >> 5) * 2048;
    const u16* vp = vpan + (size_t)(kvs >> 5) * 2048;
#pragma unroll
    for (int ks = 0; ks < 4; ++ks) ka[ks] = *(const bf16x8*)(kp + ks * 512);
#pragma unroll
    for (int dt = 0; dt < 2; ++dt)
#pragma unroll
      for (int ks = 0; ks < 2; ++ks)
        va[dt][ks] = *(const bf16x8*)(vp + dt * 1024 + ks * 16);
  }

  for (int kvb = kvs; kvb < kve; kvb += 32) {
    int nb = (kvb + 32 < kve ? kvb + 32 : kvs) >> 5;
    {
      const u16* kp = kpan + (size_t)nb * 2048;
      const u16* vp = vpan + (size_t)nb * 2048;
#pragma unroll
      for (int ks = 0; ks < 4; ++ks) kan[ks] = *(const bf16x8*)(kp + ks * 512);
#pragma unroll
      for (int dt = 0; dt < 2; ++dt)
#pragma unroll
        for (int ks = 0; ks < 2; ++ks)
          van[dt][ks] = *(const bf16x8*)(vp + dt * 1024 + ks * 16);
    }

    const bool tail = (kvb + 32 > ENC);
#pragma unroll
    for (int qc = 0; qc < 2; ++qc) {
      f32x16 sa = {};
      __builtin_amdgcn_s_setprio(1);
#pragma unroll
      for (int ks = 0; ks < 4; ++ks)
        sa = __builtin_amdgcn_mfma_f32_32x32x16_bf16(ka[ks], qb[qc][ks], sa, 0, 0, 0);
      __builtin_amdgcn_s_setprio(0);

      if (tail) {  // mask pad rows (only last step of wave 3)
#pragma unroll
        for (int r = 0; r < 16; ++r) {
          int kvr = (r & 3) + 4 * h5 + 8 * (r >> 2);
          sa[r] = (kvb + kvr >= ENC) ? -__builtin_inff() : sa[r];
        }
      }

      // P = exp2(s*C - 16*C); no online max needed (fixed shift)
      float psum = 0.f;
#pragma unroll
      for (int r = 0; r < 16; ++r) { sa[r] = exp2f(fmaf(sa[r], C, -KC)); psum += sa[r]; }
      ls[qc] += psum;

      // pack P to bf16 words (kv pairs) via native casts -> v_cvt_pk_bf16_f32
      uint32_t a[8], x[8];
#pragma unroll
      for (int i = 0; i < 8; ++i) {
        union { bf16_t b[2]; uint32_t u; } tpk;
        tpk.b[0] = (bf16_t)sa[2 * i];
        tpk.b[1] = (bf16_t)sa[2 * i + 1];
        a[i] = tpk.u;
      }
#pragma unroll
      for (int i = 0; i < 8; ++i) x[i] = (uint32_t)__shfl_xor((int)a[i], 32);
      union { uint32_t w4[4]; bf16x8 v; } pb0, pb1;
      pb0.w4[0] = h5 ? x[2] : a[0]; pb0.w4[1] = h5 ? x[3] : a[1];
      pb0.w4[2] = h5 ? a[2] : x[0]; pb0.w4[3] = h5 ? a[3] : x[1];
      pb1.w4[0] = h5 ? x[6] : a[4]; pb1.w4[1] = h5 ? x[7] : a[5];
      pb1.w4[2] = h5 ? a[6] : x[4]; pb1.w4[3] = h5 ? a[7] : x[5];

      // O^T[d][q] += V^T[d][kv] * P^T[kv][q]
      __builtin_amdgcn_s_setprio(1);
      o[qc][0] = __builtin_amdgcn_mfma_f32_32x32x16_bf16(va[0][0], pb0.v, o[qc][0], 0, 0, 0);
      o[qc][0] = __builtin_amdgcn_mfma_f32_32x32x16_bf16(va[0][1], pb1.v, o[qc][0], 0, 0, 0);
      o[qc][1] = __builtin_amdgcn_mfma_f32_32x32x16_bf16(va[1][0], pb0.v, o[qc][1], 0, 0, 0);
      o[qc][1] = __builtin_amdgcn_mfma_f32_32x32x16_bf16(va[1][1], pb1.v, o[qc][1], 0, 0, 0);
      __builtin_amdgcn_s_setprio(0);
    }

#pragma unroll
    for (int ks = 0; ks < 4; ++ks) ka[ks] = kan[ks];
#pragma unroll
    for (int dt = 0; dt < 2; ++dt)
#pragma unroll
      for (int ks = 0; ks < 2; ++ks) va[dt][ks] = van[dt][ks];
  }

  ls[0] += __shfl_xor(ls[0], 32);  // totals over both halves (same q column)
  ls[1] += __shfl_xor(ls[1], 32);

  // two combine phases (per qc), reusing the same LDS
#pragma unroll
  for (int qc = 0; qc < 2; ++qc) {
    if (qc) __syncthreads();  // prior combine reads done before overwrite
#pragma unroll
    for (int r = 0; r < 16; ++r) {
      int drow = (r & 3) + 8 * (r >> 2) + 4 * h5;
      smem[w][drow * 33 + l31] = o[qc][0][r];
      smem[w][(drow + 32) * 33 + l31] = o[qc][1][r];
    }
    if (h5 == 0) smem[w][2144 + l31] = ls[qc];
    __syncthreads();

#pragma unroll
    for (int it = 0; it < 8; ++it) {
      int item = threadIdx.x + it * 256;
      int q = item >> 6, d = item & 63;
      float L = smem[0][2144 + q] + smem[1][2144 + q] +
                smem[2][2144 + q] + smem[3][2144 + q];
      float O = smem[0][d * 33 + q] + smem[1][d * 33 + q] +
                smem[2][d * 33 + q] + smem[3][d * 33 + q];
      int qr = q0 + qc * 32 + q;
      if (qr < slen)
        attnb[(size_t)(qstart + qr) * D + head * HD + d] = f2bf(O / L);
    }
  }
}

extern "C" void kernel_launch(void* const* d_in, const int* in_sizes, int n_in,
                              void* d_out, int out_size, void* d_ws, size_t ws_size,
                              hipStream_t stream) {
  const float* hs  = (const float*)d_in[0];
  const float* chs = (const float*)d_in[1];
  const int*   seq = (const int*)d_in[2];
  const float* Wq  = (const float*)d_in[3];
  const float* bq  = (const float*)d_in[4];
  const float* Wkv = (const float*)d_in[5];
  const float* bkv = (const float*)d_in[6];
  const float* Wo  = (const float*)d_in[7];
  const float* bo  = (const float*)d_in[8];

  char* ws = (char*)d_ws;
  u16* hsb   = (u16*)(ws + 0);          // 1600*1280*2  = 4,096,000
  u16* chsb  = (u16*)(ws + 4096000);    // 6000*1280*2  = 15,360,000
  u16* Wqt   = (u16*)(ws + 19456000);   // 1280*1280*2  = 3,276,800
  u16* Wkvt  = (u16*)(ws + 22732800);   // 2560*1280*2  = 6,553,600
  u16* Wot   = (u16*)(ws + 29286400);   // 3,276,800
  u16* qhb   = (u16*)(ws + 32563200);   // 20*1632*64*2 = 4,177,920
  u16* khb   = (u16*)(ws + 36741120);   // 20*188*2048*2 = 15,400,960 (Kb tiled)
  u16* vtb   = (u16*)(ws + 52142080);   // 15,400,960 (Vb tiled)
  u16* attnb = (u16*)(ws + 67543040);   // 4,096,000  -> total 71,639,040 B

  prep_kernel<<<15900, 256, 0, stream>>>(hs, chs, Wq, Wkv, Wo, hsb, chsb, Wqt, Wkvt, Wot);
  qkv_gemm_kernel<<<1070, 256, 0, stream>>>(hsb, chsb, Wqt, Wkvt, bq, bkv, qhb, khb, vtb);
  attn_kernel<<<640, 256, 0, stream>>>(khb, vtb, qhb, seq, attnb);
  o_gemm_kernel<<<130, 256, 0, stream>>>(attnb, Wot, bo, (float*)d_out);
}

// Round 14
// 163.239 us; speedup vs baseline: 1.0837x; 1.0837x over previous
//
#include <hip/hip_runtime.h>
#include <stdint.h>

#define AS1 __attribute__((address_space(1)))
#define AS3 __attribute__((address_space(3)))

typedef __bf16 bf16_t;
typedef bf16_t bf16x8 __attribute__((ext_vector_type(8)));
typedef float  f32x4  __attribute__((ext_vector_type(4)));
typedef float  f32x16 __attribute__((ext_vector_type(16)));
typedef unsigned short u16;

constexpr int D     = 1280;
constexpr int H     = 20;
constexpr int HD    = 64;
constexpr int NQ    = 1600;
constexpr int NKV   = 6000;
constexpr int ENC   = 1500;
constexpr int QPAD  = 1632;   // NQ padded so q-row reads past the end stay in-buffer
constexpr int KVP   = 1504;   // per-request kv rows padded to 32-multiple
constexpr int KVTOT = 4 * KVP;
constexpr int KB_PER_REQ = KVP / 32;      // 47
constexpr int KB_TOT     = 4 * KB_PER_REQ; // 188

__device__ __forceinline__ u16 f2bf(float f) {
  union { float f; uint32_t u; } x; x.f = f;
  uint32_t r = (x.u + 0x7fffu + ((x.u >> 16) & 1u)) >> 16;  // RNE
  return (u16)r;
}

__device__ __forceinline__ void gload16(const void* g, void* l) {
  __builtin_amdgcn_global_load_lds((AS1 void*)g, (AS3 void*)l, 16, 0, 0);
}

// ---------------- fused prep: fp32->bf16 converts + 3 weight transposes ----------------
__device__ __forceinline__ void cvt_body(const float* __restrict__ in, u16* __restrict__ out,
                                         int i, int n4) {
  if (i >= n4) return;
  float4 v = ((const float4*)in)[i];
  ushort4 o;
  o.x = f2bf(v.x); o.y = f2bf(v.y); o.z = f2bf(v.z); o.w = f2bf(v.w);
  ((ushort4*)out)[i] = o;
}

__device__ __forceinline__ void tpose_body(const float* __restrict__ in, u16* __restrict__ out,
                                           int R, int C, int bx, int by, u16 (*tile)[33]) {
  int bc = bx * 32, br = by * 32;
  int tx = threadIdx.x & 31, ty = threadIdx.x >> 5;  // 32 x 8
#pragma unroll
  for (int i = 0; i < 32; i += 8)
    tile[ty + i][tx] = f2bf(in[(size_t)(br + ty + i) * C + bc + tx]);
  __syncthreads();
#pragma unroll
  for (int i = 0; i < 32; i += 8)
    out[(size_t)(bc + ty + i) * R + br + tx] = tile[tx][ty + i];
}

__global__ __launch_bounds__(256)
void prep_kernel(const float* __restrict__ hs, const float* __restrict__ chs,
                 const float* __restrict__ Wq, const float* __restrict__ Wkv,
                 const float* __restrict__ Wo,
                 u16* __restrict__ hsb, u16* __restrict__ chsb,
                 u16* __restrict__ Wqt, u16* __restrict__ Wkvt, u16* __restrict__ Wot) {
  __shared__ u16 tile[32][33];
  int b = blockIdx.x;
  if (b < 2000) {
    cvt_body(hs, hsb, b * 256 + threadIdx.x, 512000);
  } else if (b < 9500) {
    cvt_body(chs, chsb, (b - 2000) * 256 + threadIdx.x, 1920000);
  } else if (b < 11100) {
    int t = b - 9500;  tpose_body(Wq,  Wqt,  1280, 1280, t % 40, t / 40, tile);
  } else if (b < 14300) {
    int t = b - 11100; tpose_body(Wkv, Wkvt, 1280, 2560, t % 80, t / 80, tile);
  } else {
    int t = b - 14300; tpose_body(Wo,  Wot,  1280, 1280, t % 40, t / 40, tile);
  }
}

// ---------------- bf16 GEMM tile: C[M,N] = A[M,1280] @ Bt[N,1280]^T + bias ----------------
// R6-proven structure: 128x128 tile, 16x16x32 MFMA, 4 waves 2x2, single-buffer
// stage -> syncthreads -> compute -> syncthreads. (R7 dist-2 pipeline, R8 2-phase
// counted-vmcnt, R9 32x32 frags: all NULL or negative. FETCH=104MB matches the
// L2-capacity bound for any tile ordering — mapping converged too.)
// MODE 0: Q-proj  -> qh[h][row][hd] = (c+b)*0.125          (bf16)
// MODE 1: KV-proj -> Kb[h][kb][ks:4][kv:32][e:16]  (K blocks, n0<1280)
//                    Vb[h][kb][d:64][kv:32]        (V blocks, n0>=1280: C^T via
//                    swapped MFMA operands so stores stay coalesced)
// MODE 2: O-proj  -> outF[row*1280+col] = c+b               (fp32)
template <int MODE>
__device__ __forceinline__ void gemm_tile(
    int m0, int n0, const u16* __restrict__ A, const u16* __restrict__ Bt,
    const float* __restrict__ bias, int M,
    u16* __restrict__ outA, u16* __restrict__ outB, float* __restrict__ outF,
    u16* As, u16* Bs) {
  const int tid = threadIdx.x;
  const int lane = tid & 63, l15 = lane & 15, lg = lane >> 4;
  const int w = tid >> 6, wr = w >> 1, wc = w & 1;

  const bool vside = (MODE == 1) && (n0 >= D);

  f32x4 acc[4][4] = {};

  for (int k0 = 0; k0 < D; k0 += 64) {
#pragma unroll
    for (int p = 0; p < 4; ++p) {
      int off = p * 4096 + tid * 16;
      int lg_off = off ^ (((off >> 7) & 7) << 4);
      int row = lg_off >> 7, kb = lg_off & 127;
      int gr = m0 + row; gr = gr < M ? gr : M - 1;  // clamp M-tail
      gload16((const char*)A + ((size_t)gr * D + k0) * 2 + kb, (char*)As + off);
    }
#pragma unroll
    for (int p = 0; p < 4; ++p) {
      int off = p * 4096 + tid * 16;
      int lg_off = off ^ (((off >> 7) & 7) << 4);
      int row = lg_off >> 7, kb = lg_off & 127;
      int gr = n0 + row;  // N is always a multiple of 128
      gload16((const char*)Bt + ((size_t)gr * D + k0) * 2 + kb, (char*)Bs + off);
    }
    __syncthreads();
#pragma unroll
    for (int kk = 0; kk < 2; ++kk) {
      const int kbyte = kk * 64 + lg * 16;
      bf16x8 af[4], bfr[4];
#pragma unroll
      for (int m = 0; m < 4; ++m) {
        int row = wr * 64 + m * 16 + l15;
        int addr = ((row << 7) + kbyte) ^ ((row & 7) << 4);
        af[m] = *(const bf16x8*)((const char*)As + addr);
      }
#pragma unroll
      for (int n = 0; n < 4; ++n) {
        int row = wc * 64 + n * 16 + l15;
        int addr = ((row << 7) + kbyte) ^ ((row & 7) << 4);
        bfr[n] = *(const bf16x8*)((const char*)Bs + addr);
      }
      if (!vside) {
#pragma unroll
        for (int m = 0; m < 4; ++m)
#pragma unroll
          for (int n = 0; n < 4; ++n)
            acc[m][n] = __builtin_amdgcn_mfma_f32_16x16x32_bf16(af[m], bfr[n], acc[m][n], 0, 0, 0);
      } else {
        // C^T: D[n][m] — lane dim (col) becomes the M/kv index
#pragma unroll
        for (int m = 0; m < 4; ++m)
#pragma unroll
          for (int n = 0; n < 4; ++n)
            acc[m][n] = __builtin_amdgcn_mfma_f32_16x16x32_bf16(bfr[n], af[m], acc[m][n], 0, 0, 0);
      }
    }
    __syncthreads();
  }

  if (!vside) {
    // C/D layout: col = n-idx = lane&15, row = m-idx = (lane>>4)*4 + reg
#pragma unroll
    for (int m = 0; m < 4; ++m)
#pragma unroll
      for (int n = 0; n < 4; ++n) {
        int col = n0 + wc * 64 + n * 16 + l15;
        float bv = bias[col];
#pragma unroll
        for (int r = 0; r < 4; ++r) {
          int row = m0 + wr * 64 + m * 16 + lg * 4 + r;
          if (row >= M) continue;
          float v = acc[m][n][r] + bv;
          if (MODE == 0) {
            v *= 0.125f;  // HD^-0.5
            int h = col >> 6, hd = col & 63;
            outA[((size_t)(h * QPAD + row)) * HD + hd] = f2bf(v);
          } else if (MODE == 1) {
            int req = row / ENC, loc = row - req * ENC;
            int rr = req * KVP + loc;
            int h = col >> 6, hd = col & 63;
            int kb2 = rr >> 5, kv = rr & 31;
            outA[((size_t)((h * KB_TOT + kb2) * 4 + (hd >> 4))) * 512 + kv * 16 + (hd & 15)] = f2bf(v);
          } else {
            outF[(size_t)row * D + col] = v;
          }
        }
      }
  } else {
    // C^T: lane&15 = kv-row offset; (lane>>4)*4+reg = output-col offset
    float bvv[4][4];
#pragma unroll
    for (int n = 0; n < 4; ++n)
#pragma unroll
      for (int r = 0; r < 4; ++r)
        bvv[n][r] = bias[n0 + wc * 64 + n * 16 + lg * 4 + r];
#pragma unroll
    for (int m = 0; m < 4; ++m) {
      int gm = m0 + wr * 64 + m * 16 + l15;  // kv row (per-lane)
      int req = gm / ENC, loc = gm - req * ENC;
      int rr = req * KVP + loc;
      int kb2 = rr >> 5, kv = rr & 31;
      bool ok = gm < M;
#pragma unroll
      for (int n = 0; n < 4; ++n)
#pragma unroll
        for (int r = 0; r < 4; ++r) {
          if (!ok) continue;
          int c2 = n0 + wc * 64 + n * 16 + lg * 4 + r - D;
          int h = c2 >> 6, hd = c2 & 63;
          outB[((size_t)((h * KB_TOT + kb2) * 64 + hd)) * 32 + kv] = f2bf(acc[m][n][r] + bvv[n][r]);
        }
    }
  }
}

// ---------------- fused Q-proj + KV-proj, per-range bijective XCD swizzle ----------------
__global__ __launch_bounds__(256)
void qkv_gemm_kernel(const u16* __restrict__ hsb, const u16* __restrict__ chsb,
                     const u16* __restrict__ Wqt, const u16* __restrict__ Wkvt,
                     const float* __restrict__ bq, const float* __restrict__ bkv,
                     u16* __restrict__ qhb, u16* __restrict__ khb, u16* __restrict__ vtb) {
  __shared__ __align__(16) u16 As[128 * 64];
  __shared__ __align__(16) u16 Bs[128 * 64];
  const int bid = blockIdx.x;
  if (bid < 940) {
    const int q8 = 940 >> 3, r8 = 940 & 7;  // 117, 4
    const int xcd = bid & 7, pos = bid >> 3;
    const int wg = (xcd < r8 ? xcd * (q8 + 1) : r8 * (q8 + 1) + (xcd - r8) * q8) + pos;
    gemm_tile<1>((wg / 20) * 128, (wg % 20) * 128, chsb, Wkvt, bkv, NKV,
                 khb, vtb, nullptr, As, Bs);
  } else {
    const int b2 = bid - 940;
    const int q8 = 130 >> 3, r8 = 130 & 7;  // 16, 2
    const int xcd = b2 & 7, pos = b2 >> 3;
    const int wg = (xcd < r8 ? xcd * (q8 + 1) : r8 * (q8 + 1) + (xcd - r8) * q8) + pos;
    gemm_tile<0>((wg / 10) * 128, (wg % 10) * 128, hsb, Wqt, bq, NQ,
                 qhb, nullptr, nullptr, As, Bs);
  }
}

__global__ __launch_bounds__(256)
void o_gemm_kernel(const u16* __restrict__ attnb, const u16* __restrict__ Wot,
                   const float* __restrict__ bo, float* __restrict__ out) {
  __shared__ __align__(16) u16 As[128 * 64];
  __shared__ __align__(16) u16 Bs[128 * 64];
  const int nwg = 130, q8 = nwg >> 3, r8 = nwg & 7;
  const int xcd = blockIdx.x & 7, pos = blockIdx.x >> 3;
  const int wg = (xcd < r8 ? xcd * (q8 + 1) : r8 * (q8 + 1) + (xcd - r8) * q8) + pos;
  gemm_tile<2>((wg / 10) * 128, (wg % 10) * 128, attnb, Wot, bo, NQ,
               nullptr, nullptr, out, As, Bs);
}

// ---------------- flash attention, swapped-QK^T 32x32, fixed-shift softmax ----------------
// R11 structure (best verified): 1D grid 1280, XCD-pair-chunked swizzle, 4 waves
// kv-split, fragment-tiled K/V, fixed shift M=16. R13 change: kv loop unrolled
// by 2 with ping-pong buffers (A/B alternate compute/prefetch) — removes the 24
// register moves/step of the rotation scheme; pad-row masking hoisted to the
// tail-only call (pairs never cross ENC: wave-3 pairs end at kv 1472 < 1500).
__global__ __launch_bounds__(256)
void attn_kernel(const u16* __restrict__ kbuf, const u16* __restrict__ vbuf,
                 const u16* __restrict__ qh, const int* __restrict__ seq,
                 u16* __restrict__ attnb) {
  __shared__ __align__(16) float smem[4][2176];
  const int lane = threadIdx.x & 63;
  const int l31 = lane & 31, h5 = lane >> 5;
  const int w = threadIdx.x >> 6;

  const int xcd = blockIdx.x & 7, pos = blockIdx.x >> 3;  // pos in [0,160)
  const int g = xcd * 160 + pos;
  const int p = g >> 4, t = g & 15;   // p in [0,80): (head,req) pair; t: q-tile
  const int head = p >> 2, req = p & 3;

  int s0 = seq[0], s1 = seq[1], s2 = seq[2];
  int qstart = (req > 0 ? s0 : 0) + (req > 1 ? s1 : 0) + (req > 2 ? s2 : 0);
  int slen = seq[req];
  int q0 = t * 32;
  if (q0 >= slen) return;  // block-uniform: safe w.r.t. __syncthreads

  const u16* qrow = qh + ((size_t)(head * QPAD + qstart + q0 + l31)) * HD + h5 * 8;
  bf16x8 qb[4];
#pragma unroll
  for (int ks = 0; ks < 4; ++ks) qb[ks] = *(const bf16x8*)(qrow + ks * 16);

  const u16* kpan = kbuf + (size_t)(head * KB_TOT + req * KB_PER_REQ) * 2048 + l31 * 16 + h5 * 8;
  const u16* vpan = vbuf + (size_t)(head * KB_TOT + req * KB_PER_REQ) * 2048 + l31 * 32 + h5 * 8;
  const float C = 1.44269504088896340736f;
  const float KC = 16.0f * C;  // fixed softmax shift (scores bounded << 16)

  f32x16 o0 = {}, o1 = {};
  float ls = 0.f;

  const int kvs = w * 384;
  const int kve = (w == 3) ? ENC : kvs + 384;  // quarters: 384,384,384,348

  bf16x8 kA[4], vA[2][2], kB[4], vB[2][2];

  auto loadKV = [&](bf16x8 (&kk)[4], bf16x8 (&vv)[2][2], int blk) {
    const u16* kp = kpan + (size_t)blk * 2048;
    const u16* vp = vpan + (size_t)blk * 2048;
#pragma unroll
    for (int ks = 0; ks < 4; ++ks) kk[ks] = *(const bf16x8*)(kp + ks * 512);
#pragma unroll
    for (int dt = 0; dt < 2; ++dt)
#pragma unroll
      for (int ks = 0; ks < 2; ++ks)
        vv[dt][ks] = *(const bf16x8*)(vp + dt * 1024 + ks * 16);
  };

  auto step = [&](const bf16x8 (&kk)[4], const bf16x8 (&vv)[2][2], int kvb2, bool mask) {
    f32x16 sa = {};
    __builtin_amdgcn_s_setprio(1);
#pragma unroll
    for (int ks = 0; ks < 4; ++ks)
      sa = __builtin_amdgcn_mfma_f32_32x32x16_bf16(kk[ks], qb[ks], sa, 0, 0, 0);
    __builtin_amdgcn_s_setprio(0);

    if (mask) {  // pad rows (tail step of wave 3 only)
#pragma unroll
      for (int r = 0; r < 16; ++r) {
        int kvr = (r & 3) + 4 * h5 + 8 * (r >> 2);
        sa[r] = (kvb2 + kvr >= ENC) ? -__builtin_inff() : sa[r];
      }
    }

    // P = exp2(s*C - 16*C); no online max needed (fixed shift)
    float psum = 0.f;
#pragma unroll
    for (int r = 0; r < 16; ++r) { sa[r] = exp2f(fmaf(sa[r], C, -KC)); psum += sa[r]; }
    ls += psum;

    // pack P to bf16 words (kv pairs) via native casts -> v_cvt_pk_bf16_f32
    uint32_t a[8], x[8];
#pragma unroll
    for (int i = 0; i < 8; ++i) {
      union { bf16_t b[2]; uint32_t u; } tpk;
      tpk.b[0] = (bf16_t)sa[2 * i];
      tpk.b[1] = (bf16_t)sa[2 * i + 1];
      a[i] = tpk.u;
    }
#pragma unroll
    for (int i = 0; i < 8; ++i) x[i] = (uint32_t)__shfl_xor((int)a[i], 32);
    union { uint32_t w4[4]; bf16x8 v; } pb0, pb1;
    pb0.w4[0] = h5 ? x[2] : a[0]; pb0.w4[1] = h5 ? x[3] : a[1];
    pb0.w4[2] = h5 ? a[2] : x[0]; pb0.w4[3] = h5 ? a[3] : x[1];
    pb1.w4[0] = h5 ? x[6] : a[4]; pb1.w4[1] = h5 ? x[7] : a[5];
    pb1.w4[2] = h5 ? a[6] : x[4]; pb1.w4[3] = h5 ? a[7] : x[5];

    // O^T[d][q] += V^T[d][kv] * P^T[kv][q]
    __builtin_amdgcn_s_setprio(1);
    o0 = __builtin_amdgcn_mfma_f32_32x32x16_bf16(vv[0][0], pb0.v, o0, 0, 0, 0);
    o0 = __builtin_amdgcn_mfma_f32_32x32x16_bf16(vv[0][1], pb1.v, o0, 0, 0, 0);
    o1 = __builtin_amdgcn_mfma_f32_32x32x16_bf16(vv[1][0], pb0.v, o1, 0, 0, 0);
    o1 = __builtin_amdgcn_mfma_f32_32x32x16_bf16(vv[1][1], pb1.v, o1, 0, 0, 0);
    __builtin_amdgcn_s_setprio(0);
  };

  // ping-pong pipeline: pairs (kvb, kvb+32); prefetch distance 1; no rotation moves
  loadKV(kA, vA, kvs >> 5);
  int kvb = kvs;
  while (kvb + 64 <= kve) {
    loadKV(kB, vB, (kvb + 32) >> 5);
    step(kA, vA, kvb, false);
    int nxt = kvb + 64;
    loadKV(kA, vA, (nxt < kve ? nxt : kvs) >> 5);  // harmless wrap reload at end
    step(kB, vB, kvb + 32, false);
    kvb += 64;
  }
  if (kvb < kve)                      // tail (wave 3 only): 28 live rows, masked
    step(kA, vA, kvb, true);

  ls += __shfl_xor(ls, 32);  // total l over both halves

  // dump partials: O^T, l (no m — shift is a shared constant)
#pragma unroll
  for (int r = 0; r < 16; ++r) {
    int drow = (r & 3) + 8 * (r >> 2) + 4 * h5;
    smem[w][drow * 33 + l31] = o0[r];
    smem[w][(drow + 32) * 33 + l31] = o1[r];
  }
  if (h5 == 0) smem[w][2144 + l31] = ls;
  __syncthreads();

  // combine: plain sums (equal shifts), 2048 (q,d) items over 256 threads
#pragma unroll
  for (int it = 0; it < 8; ++it) {
    int item = threadIdx.x + it * 256;
    int q = item >> 6, d = item & 63;
    float L = smem[0][2144 + q] + smem[1][2144 + q] +
              smem[2][2144 + q] + smem[3][2144 + q];
    float O = smem[0][d * 33 + q] + smem[1][d * 33 + q] +
              smem[2][d * 33 + q] + smem[3][d * 33 + q];
    int qr = q0 + q;
    if (qr < slen)
      attnb[(size_t)(qstart + qr) * D + head * HD + d] = f2bf(O / L);
  }
}

extern "C" void kernel_launch(void* const* d_in, const int* in_sizes, int n_in,
                              void* d_out, int out_size, void* d_ws, size_t ws_size,
                              hipStream_t stream) {
  const float* hs  = (const float*)d_in[0];
  const float* chs = (const float*)d_in[1];
  const int*   seq = (const int*)d_in[2];
  const float* Wq  = (const float*)d_in[3];
  const float* bq  = (const float*)d_in[4];
  const float* Wkv = (const float*)d_in[5];
  const float* bkv = (const float*)d_in[6];
  const float* Wo  = (const float*)d_in[7];
  const float* bo  = (const float*)d_in[8];

  char* ws = (char*)d_ws;
  u16* hsb   = (u16*)(ws + 0);          // 1600*1280*2  = 4,096,000
  u16* chsb  = (u16*)(ws + 4096000);    // 6000*1280*2  = 15,360,000
  u16* Wqt   = (u16*)(ws + 19456000);   // 1280*1280*2  = 3,276,800
  u16* Wkvt  = (u16*)(ws + 22732800);   // 2560*1280*2  = 6,553,600
  u16* Wot   = (u16*)(ws + 29286400);   // 3,276,800
  u16* qhb   = (u16*)(ws + 32563200);   // 20*1632*64*2 = 4,177,920
  u16* khb   = (u16*)(ws + 36741120);   // 20*188*2048*2 = 15,400,960 (Kb tiled)
  u16* vtb   = (u16*)(ws + 52142080);   // 15,400,960 (Vb tiled)
  u16* attnb = (u16*)(ws + 67543040);   // 4,096,000  -> total 71,639,040 B

  prep_kernel<<<15900, 256, 0, stream>>>(hs, chs, Wq, Wkv, Wo, hsb, chsb, Wqt, Wkvt, Wot);
  qkv_gemm_kernel<<<1070, 256, 0, stream>>>(hsb, chsb, Wqt, Wkvt, bq, bkv, qhb, khb, vtb);
  attn_kernel<<<1280, 256, 0, stream>>>(khb, vtb, qhb, seq, attnb);
  o_gemm_kernel<<<130, 256, 0, stream>>>(attnb, Wot, bo, (float*)d_out);
}

// Round 15
// 157.364 us; speedup vs baseline: 1.1242x; 1.0373x over previous
//
#include <hip/hip_runtime.h>
#include <stdint.h>

#define AS1 __attribute__((address_space(1)))
#define AS3 __attribute__((address_space(3)))

typedef __bf16 bf16_t;
typedef bf16_t bf16x8 __attribute__((ext_vector_type(8)));
typedef float  f32x4  __attribute__((ext_vector_type(4)));
typedef float  f32x16 __attribute__((ext_vector_type(16)));
typedef unsigned short u16;

constexpr int D     = 1280;
constexpr int H     = 20;
constexpr int HD    = 64;
constexpr int NQ    = 1600;
constexpr int NKV   = 6000;
constexpr int ENC   = 1500;
constexpr int QPAD  = 1632;   // NQ padded so q-row reads past the end stay in-buffer
constexpr int KVP   = 1504;   // per-request kv rows padded to 32-multiple
constexpr int KVTOT = 4 * KVP;
constexpr int KB_PER_REQ = KVP / 32;      // 47
constexpr int KB_TOT     = 4 * KB_PER_REQ; // 188

__device__ __forceinline__ u16 f2bf(float f) {
  union { float f; uint32_t u; } x; x.f = f;
  uint32_t r = (x.u + 0x7fffu + ((x.u >> 16) & 1u)) >> 16;  // RNE
  return (u16)r;
}

__device__ __forceinline__ void gload16(const void* g, void* l) {
  __builtin_amdgcn_global_load_lds((AS1 void*)g, (AS3 void*)l, 16, 0, 0);
}

// ---------------- fused prep: fp32->bf16 converts + 3 weight transposes ----------------
__device__ __forceinline__ void cvt_body(const float* __restrict__ in, u16* __restrict__ out,
                                         int i, int n4) {
  if (i >= n4) return;
  float4 v = ((const float4*)in)[i];
  ushort4 o;
  o.x = f2bf(v.x); o.y = f2bf(v.y); o.z = f2bf(v.z); o.w = f2bf(v.w);
  ((ushort4*)out)[i] = o;
}

__device__ __forceinline__ void tpose_body(const float* __restrict__ in, u16* __restrict__ out,
                                           int R, int C, int bx, int by, u16 (*tile)[33]) {
  int bc = bx * 32, br = by * 32;
  int tx = threadIdx.x & 31, ty = threadIdx.x >> 5;  // 32 x 8
#pragma unroll
  for (int i = 0; i < 32; i += 8)
    tile[ty + i][tx] = f2bf(in[(size_t)(br + ty + i) * C + bc + tx]);
  __syncthreads();
#pragma unroll
  for (int i = 0; i < 32; i += 8)
    out[(size_t)(bc + ty + i) * R + br + tx] = tile[tx][ty + i];
}

__global__ __launch_bounds__(256)
void prep_kernel(const float* __restrict__ hs, const float* __restrict__ chs,
                 const float* __restrict__ Wq, const float* __restrict__ Wkv,
                 const float* __restrict__ Wo,
                 u16* __restrict__ hsb, u16* __restrict__ chsb,
                 u16* __restrict__ Wqt, u16* __restrict__ Wkvt, u16* __restrict__ Wot) {
  __shared__ u16 tile[32][33];
  int b = blockIdx.x;
  if (b < 2000) {
    cvt_body(hs, hsb, b * 256 + threadIdx.x, 512000);
  } else if (b < 9500) {
    cvt_body(chs, chsb, (b - 2000) * 256 + threadIdx.x, 1920000);
  } else if (b < 11100) {
    int t = b - 9500;  tpose_body(Wq,  Wqt,  1280, 1280, t % 40, t / 40, tile);
  } else if (b < 14300) {
    int t = b - 11100; tpose_body(Wkv, Wkvt, 1280, 2560, t % 80, t / 80, tile);
  } else {
    int t = b - 14300; tpose_body(Wo,  Wot,  1280, 1280, t % 40, t / 40, tile);
  }
}

// ---------------- bf16 GEMM tile: C[M,N] = A[M,1280] @ Bt[N,1280]^T + bias ----------------
// R6-proven structure: 128x128 tile, 16x16x32 MFMA, 4 waves 2x2, single-buffer
// stage -> syncthreads -> compute -> syncthreads. (R7 dist-2 pipeline, R8 2-phase
// counted-vmcnt, R9 32x32 frags: all NULL or negative — converged at this geometry.)
// MODE 0: Q-proj  -> qh[h][row][hd] = (c+b)*0.125          (bf16)
// MODE 1: KV-proj -> Kb[h][kb][ks:4][kv:32][e:16]  (K blocks, n0<1280)
//                    Vb[h][kb][d:64][kv:32]        (V blocks, n0>=1280: C^T via
//                    swapped MFMA operands so stores stay coalesced)
template <int MODE>
__device__ __forceinline__ void gemm_tile(
    int m0, int n0, const u16* __restrict__ A, const u16* __restrict__ Bt,
    const float* __restrict__ bias, int M,
    u16* __restrict__ outA, u16* __restrict__ outB, float* __restrict__ outF,
    u16* As, u16* Bs) {
  const int tid = threadIdx.x;
  const int lane = tid & 63, l15 = lane & 15, lg = lane >> 4;
  const int w = tid >> 6, wr = w >> 1, wc = w & 1;

  const bool vside = (MODE == 1) && (n0 >= D);

  f32x4 acc[4][4] = {};

  for (int k0 = 0; k0 < D; k0 += 64) {
#pragma unroll
    for (int p = 0; p < 4; ++p) {
      int off = p * 4096 + tid * 16;
      int lg_off = off ^ (((off >> 7) & 7) << 4);
      int row = lg_off >> 7, kb = lg_off & 127;
      int gr = m0 + row; gr = gr < M ? gr : M - 1;  // clamp M-tail
      gload16((const char*)A + ((size_t)gr * D + k0) * 2 + kb, (char*)As + off);
    }
#pragma unroll
    for (int p = 0; p < 4; ++p) {
      int off = p * 4096 + tid * 16;
      int lg_off = off ^ (((off >> 7) & 7) << 4);
      int row = lg_off >> 7, kb = lg_off & 127;
      int gr = n0 + row;  // N is always a multiple of 128
      gload16((const char*)Bt + ((size_t)gr * D + k0) * 2 + kb, (char*)Bs + off);
    }
    __syncthreads();
#pragma unroll
    for (int kk = 0; kk < 2; ++kk) {
      const int kbyte = kk * 64 + lg * 16;
      bf16x8 af[4], bfr[4];
#pragma unroll
      for (int m = 0; m < 4; ++m) {
        int row = wr * 64 + m * 16 + l15;
        int addr = ((row << 7) + kbyte) ^ ((row & 7) << 4);
        af[m] = *(const bf16x8*)((const char*)As + addr);
      }
#pragma unroll
      for (int n = 0; n < 4; ++n) {
        int row = wc * 64 + n * 16 + l15;
        int addr = ((row << 7) + kbyte) ^ ((row & 7) << 4);
        bfr[n] = *(const bf16x8*)((const char*)Bs + addr);
      }
      if (!vside) {
#pragma unroll
        for (int m = 0; m < 4; ++m)
#pragma unroll
          for (int n = 0; n < 4; ++n)
            acc[m][n] = __builtin_amdgcn_mfma_f32_16x16x32_bf16(af[m], bfr[n], acc[m][n], 0, 0, 0);
      } else {
        // C^T: D[n][m] — lane dim (col) becomes the M/kv index
#pragma unroll
        for (int m = 0; m < 4; ++m)
#pragma unroll
          for (int n = 0; n < 4; ++n)
            acc[m][n] = __builtin_amdgcn_mfma_f32_16x16x32_bf16(bfr[n], af[m], acc[m][n], 0, 0, 0);
      }
    }
    __syncthreads();
  }

  if (!vside) {
    // C/D layout: col = n-idx = lane&15, row = m-idx = (lane>>4)*4 + reg
#pragma unroll
    for (int m = 0; m < 4; ++m)
#pragma unroll
      for (int n = 0; n < 4; ++n) {
        int col = n0 + wc * 64 + n * 16 + l15;
        float bv = bias[col];
#pragma unroll
        for (int r = 0; r < 4; ++r) {
          int row = m0 + wr * 64 + m * 16 + lg * 4 + r;
          if (row >= M) continue;
          float v = acc[m][n][r] + bv;
          if (MODE == 0) {
            v *= 0.125f;  // HD^-0.5
            int h = col >> 6, hd = col & 63;
            outA[((size_t)(h * QPAD + row)) * HD + hd] = f2bf(v);
          } else {
            int req = row / ENC, loc = row - req * ENC;
            int rr = req * KVP + loc;
            int h = col >> 6, hd = col & 63;
            int kb2 = rr >> 5, kv = rr & 31;
            outA[((size_t)((h * KB_TOT + kb2) * 4 + (hd >> 4))) * 512 + kv * 16 + (hd & 15)] = f2bf(v);
          }
        }
      }
  } else {
    // C^T: lane&15 = kv-row offset; (lane>>4)*4+reg = output-col offset
    float bvv[4][4];
#pragma unroll
    for (int n = 0; n < 4; ++n)
#pragma unroll
      for (int r = 0; r < 4; ++r)
        bvv[n][r] = bias[n0 + wc * 64 + n * 16 + lg * 4 + r];
#pragma unroll
    for (int m = 0; m < 4; ++m) {
      int gm = m0 + wr * 64 + m * 16 + l15;  // kv row (per-lane)
      int req = gm / ENC, loc = gm - req * ENC;
      int rr = req * KVP + loc;
      int kb2 = rr >> 5, kv = rr & 31;
      bool ok = gm < M;
#pragma unroll
      for (int n = 0; n < 4; ++n)
#pragma unroll
        for (int r = 0; r < 4; ++r) {
          if (!ok) continue;
          int c2 = n0 + wc * 64 + n * 16 + lg * 4 + r - D;
          int h = c2 >> 6, hd = c2 & 63;
          outB[((size_t)((h * KB_TOT + kb2) * 64 + hd)) * 32 + kv] = f2bf(acc[m][n][r] + bvv[n][r]);
        }
    }
  }
}

// ---------------- fused Q-proj + KV-proj, per-range bijective XCD swizzle ----------------
__global__ __launch_bounds__(256)
void qkv_gemm_kernel(const u16* __restrict__ hsb, const u16* __restrict__ chsb,
                     const u16* __restrict__ Wqt, const u16* __restrict__ Wkvt,
                     const float* __restrict__ bq, const float* __restrict__ bkv,
                     u16* __restrict__ qhb, u16* __restrict__ khb, u16* __restrict__ vtb) {
  __shared__ __align__(16) u16 As[128 * 64];
  __shared__ __align__(16) u16 Bs[128 * 64];
  const int bid = blockIdx.x;
  if (bid < 940) {
    const int q8 = 940 >> 3, r8 = 940 & 7;  // 117, 4
    const int xcd = bid & 7, pos = bid >> 3;
    const int wg = (xcd < r8 ? xcd * (q8 + 1) : r8 * (q8 + 1) + (xcd - r8) * q8) + pos;
    gemm_tile<1>((wg / 20) * 128, (wg % 20) * 128, chsb, Wkvt, bkv, NKV,
                 khb, vtb, nullptr, As, Bs);
  } else {
    const int b2 = bid - 940;
    const int q8 = 130 >> 3, r8 = 130 & 7;  // 16, 2
    const int xcd = b2 & 7, pos = b2 >> 3;
    const int wg = (xcd < r8 ? xcd * (q8 + 1) : r8 * (q8 + 1) + (xcd - r8) * q8) + pos;
    gemm_tile<0>((wg / 10) * 128, (wg % 10) * 128, hsb, Wqt, bq, NQ,
                 qhb, nullptr, nullptr, As, Bs);
  }
}

// ---------------- O-proj: 128x64 tiles (260 blocks) so the single round fills all CUs ----
// Same loop skeleton as gemm_tile; B-stage halves to 8 KB; per-wave acc[4][2].
__global__ __launch_bounds__(256)
void o_gemm_kernel(const u16* __restrict__ attnb, const u16* __restrict__ Wot,
                   const float* __restrict__ bo, float* __restrict__ out) {
  __shared__ __align__(16) u16 As[128 * 64];
  __shared__ __align__(16) u16 Bs[64 * 64];
  const int nwg = 260, q8 = nwg >> 3, r8 = nwg & 7;  // 32, 4
  const int xcd = blockIdx.x & 7, pos = blockIdx.x >> 3;
  const int wg = (xcd < r8 ? xcd * (q8 + 1) : r8 * (q8 + 1) + (xcd - r8) * q8) + pos;
  const int m0 = (wg / 20) * 128, n0 = (wg % 20) * 64;

  const int tid = threadIdx.x;
  const int lane = tid & 63, l15 = lane & 15, lg = lane >> 4;
  const int w = tid >> 6, wr = w >> 1, wc = w & 1;

  f32x4 acc[4][2] = {};

  for (int k0 = 0; k0 < D; k0 += 64) {
#pragma unroll
    for (int p = 0; p < 4; ++p) {
      int off = p * 4096 + tid * 16;
      int lg_off = off ^ (((off >> 7) & 7) << 4);
      int row = lg_off >> 7, kb = lg_off & 127;
      int gr = m0 + row; gr = gr < NQ ? gr : NQ - 1;  // clamp M-tail
      gload16((const char*)attnb + ((size_t)gr * D + k0) * 2 + kb, (char*)As + off);
    }
#pragma unroll
    for (int p = 0; p < 2; ++p) {
      int off = p * 4096 + tid * 16;
      int lg_off = off ^ (((off >> 7) & 7) << 4);
      int row = lg_off >> 7, kb = lg_off & 127;
      gload16((const char*)Wot + ((size_t)(n0 + row) * D + k0) * 2 + kb, (char*)Bs + off);
    }
    __syncthreads();
#pragma unroll
    for (int kk = 0; kk < 2; ++kk) {
      const int kbyte = kk * 64 + lg * 16;
      bf16x8 af[4], bfr[2];
#pragma unroll
      for (int m = 0; m < 4; ++m) {
        int row = wr * 64 + m * 16 + l15;
        int addr = ((row << 7) + kbyte) ^ ((row & 7) << 4);
        af[m] = *(const bf16x8*)((const char*)As + addr);
      }
#pragma unroll
      for (int n = 0; n < 2; ++n) {
        int row = wc * 32 + n * 16 + l15;
        int addr = ((row << 7) + kbyte) ^ ((row & 7) << 4);
        bfr[n] = *(const bf16x8*)((const char*)Bs + addr);
      }
#pragma unroll
      for (int m = 0; m < 4; ++m)
#pragma unroll
        for (int n = 0; n < 2; ++n)
          acc[m][n] = __builtin_amdgcn_mfma_f32_16x16x32_bf16(af[m], bfr[n], acc[m][n], 0, 0, 0);
    }
    __syncthreads();
  }

#pragma unroll
  for (int m = 0; m < 4; ++m)
#pragma unroll
    for (int n = 0; n < 2; ++n) {
      int col = n0 + wc * 32 + n * 16 + l15;
      float bv = bo[col];
#pragma unroll
      for (int r = 0; r < 4; ++r) {
        int row = m0 + wr * 64 + m * 16 + lg * 4 + r;
        if (row >= NQ) continue;
        out[(size_t)row * D + col] = acc[m][n][r] + bv;
      }
    }
}

// ---------------- flash attention, swapped-QK^T 32x32, fixed-shift softmax ----------------
// R11/R13 structure: 1D grid 1280, XCD-pair-chunked swizzle, 4 waves kv-split,
// fragment-tiled K/V, fixed shift M=16, ping-pong prefetch, tail-only masking.
__global__ __launch_bounds__(256)
void attn_kernel(const u16* __restrict__ kbuf, const u16* __restrict__ vbuf,
                 const u16* __restrict__ qh, const int* __restrict__ seq,
                 u16* __restrict__ attnb) {
  __shared__ __align__(16) float smem[4][2176];
  const int lane = threadIdx.x & 63;
  const int l31 = lane & 31, h5 = lane >> 5;
  const int w = threadIdx.x >> 6;

  const int xcd = blockIdx.x & 7, pos = blockIdx.x >> 3;  // pos in [0,160)
  const int g = xcd * 160 + pos;
  const int p = g >> 4, t = g & 15;   // p in [0,80): (head,req) pair; t: q-tile
  const int head = p >> 2, req = p & 3;

  int s0 = seq[0], s1 = seq[1], s2 = seq[2];
  int qstart = (req > 0 ? s0 : 0) + (req > 1 ? s1 : 0) + (req > 2 ? s2 : 0);
  int slen = seq[req];
  int q0 = t * 32;
  if (q0 >= slen) return;  // block-uniform: safe w.r.t. __syncthreads

  const u16* qrow = qh + ((size_t)(head * QPAD + qstart + q0 + l31)) * HD + h5 * 8;
  bf16x8 qb[4];
#pragma unroll
  for (int ks = 0; ks < 4; ++ks) qb[ks] = *(const bf16x8*)(qrow + ks * 16);

  const u16* kpan = kbuf + (size_t)(head * KB_TOT + req * KB_PER_REQ) * 2048 + l31 * 16 + h5 * 8;
  const u16* vpan = vbuf + (size_t)(head * KB_TOT + req * KB_PER_REQ) * 2048 + l31 * 32 + h5 * 8;
  const float C = 1.44269504088896340736f;
  const float KC = 16.0f * C;  // fixed softmax shift (scores bounded << 16)

  f32x16 o0 = {}, o1 = {};
  float ls = 0.f;

  const int kvs = w * 384;
  const int kve = (w == 3) ? ENC : kvs + 384;  // quarters: 384,384,384,348

  bf16x8 kA[4], vA[2][2], kB[4], vB[2][2];

  auto loadKV = [&](bf16x8 (&kk)[4], bf16x8 (&vv)[2][2], int blk) {
    const u16* kp = kpan + (size_t)blk * 2048;
    const u16* vp = vpan + (size_t)blk * 2048;
#pragma unroll
    for (int ks = 0; ks < 4; ++ks) kk[ks] = *(const bf16x8*)(kp + ks * 512);
#pragma unroll
    for (int dt = 0; dt < 2; ++dt)
#pragma unroll
      for (int ks = 0; ks < 2; ++ks)
        vv[dt][ks] = *(const bf16x8*)(vp + dt * 1024 + ks * 16);
  };

  auto step = [&](const bf16x8 (&kk)[4], const bf16x8 (&vv)[2][2], int kvb2, bool mask) {
    f32x16 sa = {};
    __builtin_amdgcn_s_setprio(1);
#pragma unroll
    for (int ks = 0; ks < 4; ++ks)
      sa = __builtin_amdgcn_mfma_f32_32x32x16_bf16(kk[ks], qb[ks], sa, 0, 0, 0);
    __builtin_amdgcn_s_setprio(0);

    if (mask) {  // pad rows (tail step of wave 3 only)
#pragma unroll
      for (int r = 0; r < 16; ++r) {
        int kvr = (r & 3) + 4 * h5 + 8 * (r >> 2);
        sa[r] = (kvb2 + kvr >= ENC) ? -__builtin_inff() : sa[r];
      }
    }

    // P = exp2(s*C - 16*C); no online max needed (fixed shift)
    float psum = 0.f;
#pragma unroll
    for (int r = 0; r < 16; ++r) { sa[r] = exp2f(fmaf(sa[r], C, -KC)); psum += sa[r]; }
    ls += psum;

    // pack P to bf16 words (kv pairs) via native casts -> v_cvt_pk_bf16_f32
    uint32_t a[8], x[8];
#pragma unroll
    for (int i = 0; i < 8; ++i) {
      union { bf16_t b[2]; uint32_t u; } tpk;
      tpk.b[0] = (bf16_t)sa[2 * i];
      tpk.b[1] = (bf16_t)sa[2 * i + 1];
      a[i] = tpk.u;
    }
#pragma unroll
    for (int i = 0; i < 8; ++i) x[i] = (uint32_t)__shfl_xor((int)a[i], 32);
    union { uint32_t w4[4]; bf16x8 v; } pb0, pb1;
    pb0.w4[0] = h5 ? x[2] : a[0]; pb0.w4[1] = h5 ? x[3] : a[1];
    pb0.w4[2] = h5 ? a[2] : x[0]; pb0.w4[3] = h5 ? a[3] : x[1];
    pb1.w4[0] = h5 ? x[6] : a[4]; pb1.w4[1] = h5 ? x[7] : a[5];
    pb1.w4[2] = h5 ? a[6] : x[4]; pb1.w4[3] = h5 ? a[7] : x[5];

    // O^T[d][q] += V^T[d][kv] * P^T[kv][q]
    __builtin_amdgcn_s_setprio(1);
    o0 = __builtin_amdgcn_mfma_f32_32x32x16_bf16(vv[0][0], pb0.v, o0, 0, 0, 0);
    o0 = __builtin_amdgcn_mfma_f32_32x32x16_bf16(vv[0][1], pb1.v, o0, 0, 0, 0);
    o1 = __builtin_amdgcn_mfma_f32_32x32x16_bf16(vv[1][0], pb0.v, o1, 0, 0, 0);
    o1 = __builtin_amdgcn_mfma_f32_32x32x16_bf16(vv[1][1], pb1.v, o1, 0, 0, 0);
    __builtin_amdgcn_s_setprio(0);
  };

  // ping-pong pipeline: pairs (kvb, kvb+32); prefetch distance 1; no rotation moves
  loadKV(kA, vA, kvs >> 5);
  int kvb = kvs;
  while (kvb + 64 <= kve) {
    loadKV(kB, vB, (kvb + 32) >> 5);
    step(kA, vA, kvb, false);
    int nxt = kvb + 64;
    loadKV(kA, vA, (nxt < kve ? nxt : kvs) >> 5);  // harmless wrap reload at end
    step(kB, vB, kvb + 32, false);
    kvb += 64;
  }
  if (kvb < kve)                      // tail (wave 3 only): 28 live rows, masked
    step(kA, vA, kvb, true);

  ls += __shfl_xor(ls, 32);  // total l over both halves

  // dump partials: O^T, l (no m — shift is a shared constant)
#pragma unroll
  for (int r = 0; r < 16; ++r) {
    int drow = (r & 3) + 8 * (r >> 2) + 4 * h5;
    smem[w][drow * 33 + l31] = o0[r];
    smem[w][(drow + 32) * 33 + l31] = o1[r];
  }
  if (h5 == 0) smem[w][2144 + l31] = ls;
  __syncthreads();

  // combine: plain sums (equal shifts), 2048 (q,d) items over 256 threads
#pragma unroll
  for (int it = 0; it < 8; ++it) {
    int item = threadIdx.x + it * 256;
    int q = item >> 6, d = item & 63;
    float L = smem[0][2144 + q] + smem[1][2144 + q] +
              smem[2][2144 + q] + smem[3][2144 + q];
    float O = smem[0][d * 33 + q] + smem[1][d * 33 + q] +
              smem[2][d * 33 + q] + smem[3][d * 33 + q];
    int qr = q0 + q;
    if (qr < slen)
      attnb[(size_t)(qstart + qr) * D + head * HD + d] = f2bf(O / L);
  }
}

extern "C" void kernel_launch(void* const* d_in, const int* in_sizes, int n_in,
                              void* d_out, int out_size, void* d_ws, size_t ws_size,
                              hipStream_t stream) {
  const float* hs  = (const float*)d_in[0];
  const float* chs = (const float*)d_in[1];
  const int*   seq = (const int*)d_in[2];
  const float* Wq  = (const float*)d_in[3];
  const float* bq  = (const float*)d_in[4];
  const float* Wkv = (const float*)d_in[5];
  const float* bkv = (const float*)d_in[6];
  const float* Wo  = (const float*)d_in[7];
  const float* bo  = (const float*)d_in[8];

  char* ws = (char*)d_ws;
  u16* hsb   = (u16*)(ws + 0);          // 1600*1280*2  = 4,096,000
  u16* chsb  = (u16*)(ws + 4096000);    // 6000*1280*2  = 15,360,000
  u16* Wqt   = (u16*)(ws + 19456000);   // 1280*1280*2  = 3,276,800
  u16* Wkvt  = (u16*)(ws + 22732800);   // 2560*1280*2  = 6,553,600
  u16* Wot   = (u16*)(ws + 29286400);   // 3,276,800
  u16* qhb   = (u16*)(ws + 32563200);   // 20*1632*64*2 = 4,177,920
  u16* khb   = (u16*)(ws + 36741120);   // 20*188*2048*2 = 15,400,960 (Kb tiled)
  u16* vtb   = (u16*)(ws + 52142080);   // 15,400,960 (Vb tiled)
  u16* attnb = (u16*)(ws + 67543040);   // 4,096,000  -> total 71,639,040 B

  prep_kernel<<<15900, 256, 0, stream>>>(hs, chs, Wq, Wkv, Wo, hsb, chsb, Wqt, Wkvt, Wot);
  qkv_gemm_kernel<<<1070, 256, 0, stream>>>(hsb, chsb, Wqt, Wkvt, bq, bkv, qhb, khb, vtb);
  attn_kernel<<<1280, 256, 0, stream>>>(khb, vtb, qhb, seq, attnb);
  o_gemm_kernel<<<260, 256, 0, stream>>>(attnb, Wot, bo, (float*)d_out);
}

// Round 16
// 152.986 us; speedup vs baseline: 1.1564x; 1.0286x over previous
//
#include <hip/hip_runtime.h>
#include <stdint.h>

#define AS1 __attribute__((address_space(1)))
#define AS3 __attribute__((address_space(3)))

typedef __bf16 bf16_t;
typedef bf16_t bf16x8 __attribute__((ext_vector_type(8)));
typedef float  f32x4  __attribute__((ext_vector_type(4)));
typedef float  f32x16 __attribute__((ext_vector_type(16)));
typedef unsigned short u16;

constexpr int D     = 1280;
constexpr int H     = 20;
constexpr int HD    = 64;
constexpr int NQ    = 1600;
constexpr int NKV   = 6000;
constexpr int ENC   = 1500;
constexpr int QPAD  = 1632;   // NQ padded so q-row reads past the end stay in-buffer
constexpr int KVP   = 1504;   // per-request kv rows padded to 32-multiple
constexpr int KVTOT = 4 * KVP;
constexpr int KB_PER_REQ = KVP / 32;      // 47
constexpr int KB_TOT     = 4 * KB_PER_REQ; // 188

__device__ __forceinline__ u16 f2bf(float f) {
  union { float f; uint32_t u; } x; x.f = f;
  uint32_t r = (x.u + 0x7fffu + ((x.u >> 16) & 1u)) >> 16;  // RNE
  return (u16)r;
}

__device__ __forceinline__ void gload16(const void* g, void* l) {
  __builtin_amdgcn_global_load_lds((AS1 void*)g, (AS3 void*)l, 16, 0, 0);
}

// ---------------- fused prep: fp32->bf16 converts + 3 weight transposes ----------------
__device__ __forceinline__ void cvt_body(const float* __restrict__ in, u16* __restrict__ out,
                                         int i, int n4) {
  if (i >= n4) return;
  float4 v = ((const float4*)in)[i];
  ushort4 o;
  o.x = f2bf(v.x); o.y = f2bf(v.y); o.z = f2bf(v.z); o.w = f2bf(v.w);
  ((ushort4*)out)[i] = o;
}

__device__ __forceinline__ void tpose_body(const float* __restrict__ in, u16* __restrict__ out,
                                           int R, int C, int bx, int by, u16 (*tile)[33]) {
  int bc = bx * 32, br = by * 32;
  int tx = threadIdx.x & 31, ty = threadIdx.x >> 5;  // 32 x 8
#pragma unroll
  for (int i = 0; i < 32; i += 8)
    tile[ty + i][tx] = f2bf(in[(size_t)(br + ty + i) * C + bc + tx]);
  __syncthreads();
#pragma unroll
  for (int i = 0; i < 32; i += 8)
    out[(size_t)(bc + ty + i) * R + br + tx] = tile[tx][ty + i];
}

__global__ __launch_bounds__(256)
void prep_kernel(const float* __restrict__ hs, const float* __restrict__ chs,
                 const float* __restrict__ Wq, const float* __restrict__ Wkv,
                 const float* __restrict__ Wo,
                 u16* __restrict__ hsb, u16* __restrict__ chsb,
                 u16* __restrict__ Wqt, u16* __restrict__ Wkvt, u16* __restrict__ Wot) {
  __shared__ u16 tile[32][33];
  int b = blockIdx.x;
  if (b < 2000) {
    cvt_body(hs, hsb, b * 256 + threadIdx.x, 512000);
  } else if (b < 9500) {
    cvt_body(chs, chsb, (b - 2000) * 256 + threadIdx.x, 1920000);
  } else if (b < 11100) {
    int t = b - 9500;  tpose_body(Wq,  Wqt,  1280, 1280, t % 40, t / 40, tile);
  } else if (b < 14300) {
    int t = b - 11100; tpose_body(Wkv, Wkvt, 1280, 2560, t % 80, t / 80, tile);
  } else {
    int t = b - 14300; tpose_body(Wo,  Wot,  1280, 1280, t % 40, t / 40, tile);
  }
}

// ---------------- bf16 GEMM tile: C[M,N] = A[M,1280] @ Bt[N,1280]^T + bias ----------------
// R6-proven structure: 128x128 tile, 16x16x32 MFMA, 4 waves 2x2, single-buffer
// stage -> syncthreads -> compute -> syncthreads. (R7/R8/R9 redesigns all regressed —
// converged at this geometry.)
// MODE 0: Q-proj  -> qh[h][row][hd] = (c+b)*0.125          (bf16)
// MODE 1: KV-proj -> Kb[h][kb][ks:4][kv:32][e:16]  (K blocks, n0<1280)
//                    Vb[h][kb][d:64][kv:32]        (V blocks, n0>=1280: C^T via
//                    swapped MFMA operands so stores stay coalesced)
template <int MODE>
__device__ __forceinline__ void gemm_tile(
    int m0, int n0, const u16* __restrict__ A, const u16* __restrict__ Bt,
    const float* __restrict__ bias, int M,
    u16* __restrict__ outA, u16* __restrict__ outB, float* __restrict__ outF,
    u16* As, u16* Bs) {
  const int tid = threadIdx.x;
  const int lane = tid & 63, l15 = lane & 15, lg = lane >> 4;
  const int w = tid >> 6, wr = w >> 1, wc = w & 1;

  const bool vside = (MODE == 1) && (n0 >= D);

  f32x4 acc[4][4] = {};

  for (int k0 = 0; k0 < D; k0 += 64) {
#pragma unroll
    for (int p = 0; p < 4; ++p) {
      int off = p * 4096 + tid * 16;
      int lg_off = off ^ (((off >> 7) & 7) << 4);
      int row = lg_off >> 7, kb = lg_off & 127;
      int gr = m0 + row; gr = gr < M ? gr : M - 1;  // clamp M-tail
      gload16((const char*)A + ((size_t)gr * D + k0) * 2 + kb, (char*)As + off);
    }
#pragma unroll
    for (int p = 0; p < 4; ++p) {
      int off = p * 4096 + tid * 16;
      int lg_off = off ^ (((off >> 7) & 7) << 4);
      int row = lg_off >> 7, kb = lg_off & 127;
      int gr = n0 + row;  // N is always a multiple of 128
      gload16((const char*)Bt + ((size_t)gr * D + k0) * 2 + kb, (char*)Bs + off);
    }
    __syncthreads();
#pragma unroll
    for (int kk = 0; kk < 2; ++kk) {
      const int kbyte = kk * 64 + lg * 16;
      bf16x8 af[4], bfr[4];
#pragma unroll
      for (int m = 0; m < 4; ++m) {
        int row = wr * 64 + m * 16 + l15;
        int addr = ((row << 7) + kbyte) ^ ((row & 7) << 4);
        af[m] = *(const bf16x8*)((const char*)As + addr);
      }
#pragma unroll
      for (int n = 0; n < 4; ++n) {
        int row = wc * 64 + n * 16 + l15;
        int addr = ((row << 7) + kbyte) ^ ((row & 7) << 4);
        bfr[n] = *(const bf16x8*)((const char*)Bs + addr);
      }
      if (!vside) {
#pragma unroll
        for (int m = 0; m < 4; ++m)
#pragma unroll
          for (int n = 0; n < 4; ++n)
            acc[m][n] = __builtin_amdgcn_mfma_f32_16x16x32_bf16(af[m], bfr[n], acc[m][n], 0, 0, 0);
      } else {
        // C^T: D[n][m] — lane dim (col) becomes the M/kv index
#pragma unroll
        for (int m = 0; m < 4; ++m)
#pragma unroll
          for (int n = 0; n < 4; ++n)
            acc[m][n] = __builtin_amdgcn_mfma_f32_16x16x32_bf16(bfr[n], af[m], acc[m][n], 0, 0, 0);
      }
    }
    __syncthreads();
  }

  if (!vside) {
    // C/D layout: col = n-idx = lane&15, row = m-idx = (lane>>4)*4 + reg
#pragma unroll
    for (int m = 0; m < 4; ++m)
#pragma unroll
      for (int n = 0; n < 4; ++n) {
        int col = n0 + wc * 64 + n * 16 + l15;
        float bv = bias[col];
#pragma unroll
        for (int r = 0; r < 4; ++r) {
          int row = m0 + wr * 64 + m * 16 + lg * 4 + r;
          if (row >= M) continue;
          float v = acc[m][n][r] + bv;
          if (MODE == 0) {
            v *= 0.125f;  // HD^-0.5
            int h = col >> 6, hd = col & 63;
            outA[((size_t)(h * QPAD + row)) * HD + hd] = f2bf(v);
          } else {
            int req = row / ENC, loc = row - req * ENC;
            int rr = req * KVP + loc;
            int h = col >> 6, hd = col & 63;
            int kb2 = rr >> 5, kv = rr & 31;
            outA[((size_t)((h * KB_TOT + kb2) * 4 + (hd >> 4))) * 512 + kv * 16 + (hd & 15)] = f2bf(v);
          }
        }
      }
  } else {
    // C^T: lane&15 = kv-row offset; (lane>>4)*4+reg = output-col offset
    float bvv[4][4];
#pragma unroll
    for (int n = 0; n < 4; ++n)
#pragma unroll
      for (int r = 0; r < 4; ++r)
        bvv[n][r] = bias[n0 + wc * 64 + n * 16 + lg * 4 + r];
#pragma unroll
    for (int m = 0; m < 4; ++m) {
      int gm = m0 + wr * 64 + m * 16 + l15;  // kv row (per-lane)
      int req = gm / ENC, loc = gm - req * ENC;
      int rr = req * KVP + loc;
      int kb2 = rr >> 5, kv = rr & 31;
      bool ok = gm < M;
#pragma unroll
      for (int n = 0; n < 4; ++n)
#pragma unroll
        for (int r = 0; r < 4; ++r) {
          if (!ok) continue;
          int c2 = n0 + wc * 64 + n * 16 + lg * 4 + r - D;
          int h = c2 >> 6, hd = c2 & 63;
          outB[((size_t)((h * KB_TOT + kb2) * 64 + hd)) * 32 + kv] = f2bf(acc[m][n][r] + bvv[n][r]);
        }
    }
  }
}

// ---------------- fused Q-proj + KV-proj, per-range bijective XCD swizzle ----------------
__global__ __launch_bounds__(256)
void qkv_gemm_kernel(const u16* __restrict__ hsb, const u16* __restrict__ chsb,
                     const u16* __restrict__ Wqt, const u16* __restrict__ Wkvt,
                     const float* __restrict__ bq, const float* __restrict__ bkv,
                     u16* __restrict__ qhb, u16* __restrict__ khb, u16* __restrict__ vtb) {
  __shared__ __align__(16) u16 As[128 * 64];
  __shared__ __align__(16) u16 Bs[128 * 64];
  const int bid = blockIdx.x;
  if (bid < 940) {
    const int q8 = 940 >> 3, r8 = 940 & 7;  // 117, 4
    const int xcd = bid & 7, pos = bid >> 3;
    const int wg = (xcd < r8 ? xcd * (q8 + 1) : r8 * (q8 + 1) + (xcd - r8) * q8) + pos;
    gemm_tile<1>((wg / 20) * 128, (wg % 20) * 128, chsb, Wkvt, bkv, NKV,
                 khb, vtb, nullptr, As, Bs);
  } else {
    const int b2 = bid - 940;
    const int q8 = 130 >> 3, r8 = 130 & 7;  // 16, 2
    const int xcd = b2 & 7, pos = b2 >> 3;
    const int wg = (xcd < r8 ? xcd * (q8 + 1) : r8 * (q8 + 1) + (xcd - r8) * q8) + pos;
    gemm_tile<0>((wg / 10) * 128, (wg % 10) * 128, hsb, Wqt, bq, NQ,
                 qhb, nullptr, nullptr, As, Bs);
  }
}

// ---------------- O-proj: 128x64 tiles (260 blocks) so the single round fills all CUs ----
__global__ __launch_bounds__(256)
void o_gemm_kernel(const u16* __restrict__ attnb, const u16* __restrict__ Wot,
                   const float* __restrict__ bo, float* __restrict__ out) {
  __shared__ __align__(16) u16 As[128 * 64];
  __shared__ __align__(16) u16 Bs[64 * 64];
  const int nwg = 260, q8 = nwg >> 3, r8 = nwg & 7;  // 32, 4
  const int xcd = blockIdx.x & 7, pos = blockIdx.x >> 3;
  const int wg = (xcd < r8 ? xcd * (q8 + 1) : r8 * (q8 + 1) + (xcd - r8) * q8) + pos;
  const int m0 = (wg / 20) * 128, n0 = (wg % 20) * 64;

  const int tid = threadIdx.x;
  const int lane = tid & 63, l15 = lane & 15, lg = lane >> 4;
  const int w = tid >> 6, wr = w >> 1, wc = w & 1;

  f32x4 acc[4][2] = {};

  for (int k0 = 0; k0 < D; k0 += 64) {
#pragma unroll
    for (int p = 0; p < 4; ++p) {
      int off = p * 4096 + tid * 16;
      int lg_off = off ^ (((off >> 7) & 7) << 4);
      int row = lg_off >> 7, kb = lg_off & 127;
      int gr = m0 + row; gr = gr < NQ ? gr : NQ - 1;  // clamp M-tail
      gload16((const char*)attnb + ((size_t)gr * D + k0) * 2 + kb, (char*)As + off);
    }
#pragma unroll
    for (int p = 0; p < 2; ++p) {
      int off = p * 4096 + tid * 16;
      int lg_off = off ^ (((off >> 7) & 7) << 4);
      int row = lg_off >> 7, kb = lg_off & 127;
      gload16((const char*)Wot + ((size_t)(n0 + row) * D + k0) * 2 + kb, (char*)Bs + off);
    }
    __syncthreads();
#pragma unroll
    for (int kk = 0; kk < 2; ++kk) {
      const int kbyte = kk * 64 + lg * 16;
      bf16x8 af[4], bfr[2];
#pragma unroll
      for (int m = 0; m < 4; ++m) {
        int row = wr * 64 + m * 16 + l15;
        int addr = ((row << 7) + kbyte) ^ ((row & 7) << 4);
        af[m] = *(const bf16x8*)((const char*)As + addr);
      }
#pragma unroll
      for (int n = 0; n < 2; ++n) {
        int row = wc * 32 + n * 16 + l15;
        int addr = ((row << 7) + kbyte) ^ ((row & 7) << 4);
        bfr[n] = *(const bf16x8*)((const char*)Bs + addr);
      }
#pragma unroll
      for (int m = 0; m < 4; ++m)
#pragma unroll
        for (int n = 0; n < 2; ++n)
          acc[m][n] = __builtin_amdgcn_mfma_f32_16x16x32_bf16(af[m], bfr[n], acc[m][n], 0, 0, 0);
    }
    __syncthreads();
  }

#pragma unroll
  for (int m = 0; m < 4; ++m)
#pragma unroll
    for (int n = 0; n < 2; ++n) {
      int col = n0 + wc * 32 + n * 16 + l15;
      float bv = bo[col];
#pragma unroll
      for (int r = 0; r < 4; ++r) {
        int row = m0 + wr * 64 + m * 16 + lg * 4 + r;
        if (row >= NQ) continue;
        out[(size_t)row * D + col] = acc[m][n][r] + bv;
      }
    }
}

// ---------------- flash attention, swapped-QK^T 32x32, fixed-shift softmax ----------------
// R15: TLP over ILP — no register prefetch (T14 null at high occupancy, m219; saves
// ~32 VGPR), __launch_bounds__(256,4) forces <=128 VGPR = 4 waves/SIMD, LDS halved
// to 17.4 KB via two-pass combine. K/V is L2-hot (FETCH 17 MB) so the exposed
// per-step load latency (~200-400 cy) hides under 4x co-resident waves.
__global__ __launch_bounds__(256, 4)
void attn_kernel(const u16* __restrict__ kbuf, const u16* __restrict__ vbuf,
                 const u16* __restrict__ qh, const int* __restrict__ seq,
                 u16* __restrict__ attnb) {
  // per-wave: O^T half (32 d-rows x 33) = 1056 floats + ls at [1056..1088)
  __shared__ __align__(16) float smem[4][1088];
  const int lane = threadIdx.x & 63;
  const int l31 = lane & 31, h5 = lane >> 5;
  const int w = threadIdx.x >> 6;

  const int xcd = blockIdx.x & 7, pos = blockIdx.x >> 3;  // pos in [0,160)
  const int g = xcd * 160 + pos;
  const int p = g >> 4, t = g & 15;   // p in [0,80): (head,req) pair; t: q-tile
  const int head = p >> 2, req = p & 3;

  int s0 = seq[0], s1 = seq[1], s2 = seq[2];
  int qstart = (req > 0 ? s0 : 0) + (req > 1 ? s1 : 0) + (req > 2 ? s2 : 0);
  int slen = seq[req];
  int q0 = t * 32;
  if (q0 >= slen) return;  // block-uniform: safe w.r.t. __syncthreads

  const u16* qrow = qh + ((size_t)(head * QPAD + qstart + q0 + l31)) * HD + h5 * 8;
  bf16x8 qb[4];
#pragma unroll
  for (int ks = 0; ks < 4; ++ks) qb[ks] = *(const bf16x8*)(qrow + ks * 16);

  const u16* kpan = kbuf + (size_t)(head * KB_TOT + req * KB_PER_REQ) * 2048 + l31 * 16 + h5 * 8;
  const u16* vpan = vbuf + (size_t)(head * KB_TOT + req * KB_PER_REQ) * 2048 + l31 * 32 + h5 * 8;
  const float C = 1.44269504088896340736f;
  const float KC = 16.0f * C;  // fixed softmax shift (scores bounded << 16)

  f32x16 o0 = {}, o1 = {};
  float ls = 0.f;

  const int kvs = w * 384;
  const int kve = (w == 3) ? ENC : kvs + 384;  // quarters: 384,384,384,348

  auto step = [&](int kvb2, bool mask) {
    // single-buffer K/V frag loads (no prefetch: TLP hides the L2 latency)
    const u16* kp = kpan + (size_t)(kvb2 >> 5) * 2048;
    const u16* vp = vpan + (size_t)(kvb2 >> 5) * 2048;
    bf16x8 kk[4], vv[2][2];
#pragma unroll
    for (int ks = 0; ks < 4; ++ks) kk[ks] = *(const bf16x8*)(kp + ks * 512);
#pragma unroll
    for (int dt = 0; dt < 2; ++dt)
#pragma unroll
      for (int ks = 0; ks < 2; ++ks)
        vv[dt][ks] = *(const bf16x8*)(vp + dt * 1024 + ks * 16);

    f32x16 sa = {};
    __builtin_amdgcn_s_setprio(1);
#pragma unroll
    for (int ks = 0; ks < 4; ++ks)
      sa = __builtin_amdgcn_mfma_f32_32x32x16_bf16(kk[ks], qb[ks], sa, 0, 0, 0);
    __builtin_amdgcn_s_setprio(0);

    if (mask) {  // pad rows (tail step of wave 3 only)
#pragma unroll
      for (int r = 0; r < 16; ++r) {
        int kvr = (r & 3) + 4 * h5 + 8 * (r >> 2);
        sa[r] = (kvb2 + kvr >= ENC) ? -__builtin_inff() : sa[r];
      }
    }

    // P = exp2(s*C - 16*C); no online max needed (fixed shift)
    float psum = 0.f;
#pragma unroll
    for (int r = 0; r < 16; ++r) { sa[r] = exp2f(fmaf(sa[r], C, -KC)); psum += sa[r]; }
    ls += psum;

    // pack P to bf16 words (kv pairs) via native casts -> v_cvt_pk_bf16_f32
    uint32_t a[8], x[8];
#pragma unroll
    for (int i = 0; i < 8; ++i) {
      union { bf16_t b[2]; uint32_t u; } tpk;
      tpk.b[0] = (bf16_t)sa[2 * i];
      tpk.b[1] = (bf16_t)sa[2 * i + 1];
      a[i] = tpk.u;
    }
#pragma unroll
    for (int i = 0; i < 8; ++i) x[i] = (uint32_t)__shfl_xor((int)a[i], 32);
    union { uint32_t w4[4]; bf16x8 v; } pb0, pb1;
    pb0.w4[0] = h5 ? x[2] : a[0]; pb0.w4[1] = h5 ? x[3] : a[1];
    pb0.w4[2] = h5 ? a[2] : x[0]; pb0.w4[3] = h5 ? a[3] : x[1];
    pb1.w4[0] = h5 ? x[6] : a[4]; pb1.w4[1] = h5 ? x[7] : a[5];
    pb1.w4[2] = h5 ? a[6] : x[4]; pb1.w4[3] = h5 ? a[7] : x[5];

    // O^T[d][q] += V^T[d][kv] * P^T[kv][q]
    __builtin_amdgcn_s_setprio(1);
    o0 = __builtin_amdgcn_mfma_f32_32x32x16_bf16(vv[0][0], pb0.v, o0, 0, 0, 0);
    o0 = __builtin_amdgcn_mfma_f32_32x32x16_bf16(vv[0][1], pb1.v, o0, 0, 0, 0);
    o1 = __builtin_amdgcn_mfma_f32_32x32x16_bf16(vv[1][0], pb0.v, o1, 0, 0, 0);
    o1 = __builtin_amdgcn_mfma_f32_32x32x16_bf16(vv[1][1], pb1.v, o1, 0, 0, 0);
    __builtin_amdgcn_s_setprio(0);
  };

  int kvb = kvs;
  for (; kvb + 32 <= kve; kvb += 32) step(kvb, false);
  if (kvb < kve) step(kvb, true);   // wave-3 tail: 28 live rows, masked

  ls += __shfl_xor(ls, 32);  // total l over both halves

  // two-pass combine (halved LDS): pass 0 = d rows 0..31 (o0), pass 1 = 32..63 (o1)
#pragma unroll
  for (int pass = 0; pass < 2; ++pass) {
    if (pass) __syncthreads();  // pass-0 combine reads done before overwrite
#pragma unroll
    for (int r = 0; r < 16; ++r) {
      int drow = (r & 3) + 8 * (r >> 2) + 4 * h5;  // 0..31
      smem[w][drow * 33 + l31] = pass ? o1[r] : o0[r];
    }
    if (pass == 0 && h5 == 0) smem[w][1056 + l31] = ls;  // written once, reused
    __syncthreads();

    // 1024 (q, d-half) items over 256 threads; d consecutive per tid -> coalesced
#pragma unroll
    for (int it = 0; it < 4; ++it) {
      int item = threadIdx.x + it * 256;
      int q = item >> 5, d = item & 31;
      float L = smem[0][1056 + q] + smem[1][1056 + q] +
                smem[2][1056 + q] + smem[3][1056 + q];
      float O = smem[0][d * 33 + q] + smem[1][d * 33 + q] +
                smem[2][d * 33 + q] + smem[3][d * 33 + q];
      int qr = q0 + q;
      if (qr < slen)
        attnb[(size_t)(qstart + qr) * D + head * HD + pass * 32 + d] = f2bf(O / L);
    }
  }
}

extern "C" void kernel_launch(void* const* d_in, const int* in_sizes, int n_in,
                              void* d_out, int out_size, void* d_ws, size_t ws_size,
                              hipStream_t stream) {
  const float* hs  = (const float*)d_in[0];
  const float* chs = (const float*)d_in[1];
  const int*   seq = (const int*)d_in[2];
  const float* Wq  = (const float*)d_in[3];
  const float* bq  = (const float*)d_in[4];
  const float* Wkv = (const float*)d_in[5];
  const float* bkv = (const float*)d_in[6];
  const float* Wo  = (const float*)d_in[7];
  const float* bo  = (const float*)d_in[8];

  char* ws = (char*)d_ws;
  u16* hsb   = (u16*)(ws + 0);          // 1600*1280*2  = 4,096,000
  u16* chsb  = (u16*)(ws + 4096000);    // 6000*1280*2  = 15,360,000
  u16* Wqt   = (u16*)(ws + 19456000);   // 1280*1280*2  = 3,276,800
  u16* Wkvt  = (u16*)(ws + 22732800);   // 2560*1280*2  = 6,553,600
  u16* Wot   = (u16*)(ws + 29286400);   // 3,276,800
  u16* qhb   = (u16*)(ws + 32563200);   // 20*1632*64*2 = 4,177,920
  u16* khb   = (u16*)(ws + 36741120);   // 20*188*2048*2 = 15,400,960 (Kb tiled)
  u16* vtb   = (u16*)(ws + 52142080);   // 15,400,960 (Vb tiled)
  u16* attnb = (u16*)(ws + 67543040);   // 4,096,000  -> total 71,639,040 B

  prep_kernel<<<15900, 256, 0, stream>>>(hs, chs, Wq, Wkv, Wo, hsb, chsb, Wqt, Wkvt, Wot);
  qkv_gemm_kernel<<<1070, 256, 0, stream>>>(hsb, chsb, Wqt, Wkvt, bq, bkv, qhb, khb, vtb);
  attn_kernel<<<1280, 256, 0, stream>>>(khb, vtb, qhb, seq, attnb);
  o_gemm_kernel<<<260, 256, 0, stream>>>(attnb, Wot, bo, (float*)d_out);
}